// Round 6
// baseline (99.583 us; speedup 1.0000x reference)
//
#include <hip/hip_runtime.h>

// Coords are all {0,1}; STRIDES is a mixed-radix positional encoding, so each
// row maps bijectively to a 16-bit pattern. Whole op = 65536-bin float
// histogram + gather.
//
// R0-R2: global fp32 atomicAdd executes at the memory-side coherence point
// regardless of scope (~19G ops/s cap) -> no global atomics anywhere.
// R4: LDS-partitioned build (8 parts x 8192 bins, 1024-thr blocks) works.
// R5: extract was MLP-starved (2.7 TB/s effective) and wasted a pat_q
// round-trip. Now: 4-rows/thread unrolled extract (16 int4 loads in flight,
// ushort4 store) and gather fused with query-pattern computation.

#define REL_W 16
#define NBINS 65536
#define NPART 8
#define BPP 8192        // bins per partition (32 KB as floats)
#define NSLICES 64
#define BUILD_BLK 1024
#define BLK 256

typedef unsigned short ushort8_t __attribute__((ext_vector_type(8)));

__device__ __forceinline__ unsigned pat_from_regs(const int4* r) {
    unsigned pat = 0;
#pragma unroll
    for (int k = 0; k < 4; ++k) {
        int4 v = r[k];
        pat |= (unsigned)(v.x & 1) << (k * 4 + 0);
        pat |= (unsigned)(v.y & 1) << (k * 4 + 1);
        pat |= (unsigned)(v.z & 1) << (k * 4 + 2);
        pat |= (unsigned)(v.w & 1) << (k * 4 + 3);
    }
    return pat;
}

__device__ __forceinline__ unsigned pattern_of(const int* __restrict__ row) {
    int4 r[4];
    const int4* p = reinterpret_cast<const int4*>(row);
#pragma unroll
    for (int k = 0; k < 4; ++k) r[k] = p[k];
    return pat_from_regs(r);
}

// 4 rows per thread: 16 independent int4 loads in flight, ushort4 store
__global__ __launch_bounds__(BLK) void extract_stored(const int* __restrict__ coords,
                                                      unsigned short* __restrict__ pats, int n) {
    int t = blockIdx.x * blockDim.x + threadIdx.x;
    int base = t * 4;
    if (base + 4 <= n) {
        const int4* p = reinterpret_cast<const int4*>(coords) + (size_t)base * 4;
        int4 r[16];
#pragma unroll
        for (int k = 0; k < 16; ++k) r[k] = p[k];
        ushort4 o;
        o.x = (unsigned short)pat_from_regs(r + 0);
        o.y = (unsigned short)pat_from_regs(r + 4);
        o.z = (unsigned short)pat_from_regs(r + 8);
        o.w = (unsigned short)pat_from_regs(r + 12);
        *reinterpret_cast<ushort4*>(pats + base) = o;
    } else {
        for (int i = base; i < n; ++i)
            pats[i] = (unsigned short)pattern_of(coords + (size_t)i * REL_W);
    }
}

// gather fused with query pattern extraction: no pat_q round-trip
__global__ __launch_bounds__(BLK) void gather_fused(const int* __restrict__ queries,
                                                    const float* __restrict__ h,
                                                    float* __restrict__ out, int n) {
    int t = blockIdx.x * blockDim.x + threadIdx.x;
    int base = t * 4;
    if (base + 4 <= n) {
        const int4* p = reinterpret_cast<const int4*>(queries) + (size_t)base * 4;
        int4 r[16];
#pragma unroll
        for (int k = 0; k < 16; ++k) r[k] = p[k];
        float4 o;
        o.x = h[pat_from_regs(r + 0)];
        o.y = h[pat_from_regs(r + 4)];
        o.z = h[pat_from_regs(r + 8)];
        o.w = h[pat_from_regs(r + 12)];
        *reinterpret_cast<float4*>(out + base) = o;
    } else {
        for (int i = base; i < n; ++i)
            out[i] = h[pattern_of(queries + (size_t)i * REL_W)];
    }
}

__global__ __launch_bounds__(BUILD_BLK) void build_parts(const unsigned short* __restrict__ pats,
                                                         const float* __restrict__ vals,
                                                         float* __restrict__ part_hists, int n) {
    __shared__ float lh[BPP];
    unsigned part  = blockIdx.x / NSLICES;
    unsigned slice = blockIdx.x % NSLICES;
    for (int b = threadIdx.x; b < BPP; b += BUILD_BLK) lh[b] = 0.0f;
    __syncthreads();

    int per = ((n + NSLICES - 1) / NSLICES + 7) & ~7;
    int lo = (int)slice * per;
    int hi = min(n, lo + per);

    if (lo < hi) {
        int m = hi - lo;
        int nvec = m >> 3;
        const ushort8_t* pv = reinterpret_cast<const ushort8_t*>(pats + lo);
        const float4*    vv = reinterpret_cast<const float4*>(vals + lo);
        for (int v = threadIdx.x; v < nvec; v += BUILD_BLK) {
            ushort8_t p8 = pv[v];
            float4 v0 = vv[2 * v];
            float4 v1 = vv[2 * v + 1];
            float vsc[8] = {v0.x, v0.y, v0.z, v0.w, v1.x, v1.y, v1.z, v1.w};
#pragma unroll
            for (int k = 0; k < 8; ++k) {
                unsigned pat = p8[k];
                if ((pat >> 13) == part)
                    atomicAdd(&lh[pat & (BPP - 1)], vsc[k]);   // ds_add_f32, on-CU
            }
        }
        for (int i = lo + (nvec << 3) + (int)threadIdx.x; i < hi; i += BUILD_BLK) {
            unsigned pat = pats[i];
            if ((pat >> 13) == part)
                atomicAdd(&lh[pat & (BPP - 1)], vals[i]);
        }
    }
    __syncthreads();
    float* dst = part_hists + (size_t)blockIdx.x * BPP;
    for (int b = threadIdx.x; b < BPP; b += BUILD_BLK) dst[b] = lh[b];
}

__global__ void reduce_parts(const float* __restrict__ part_hists, float* __restrict__ final_h) {
    int g = blockIdx.x * blockDim.x + threadIdx.x;   // bin 0..65535
    unsigned part = (unsigned)g >> 13;
    unsigned b = (unsigned)g & (BPP - 1);
    const float* src = part_hists + ((size_t)part * NSLICES) * BPP + b;
    float s = 0.0f;
#pragma unroll 8
    for (int sl = 0; sl < NSLICES; ++sl) s += src[(size_t)sl * BPP];
    final_h[g] = s;
}

// ---- fallback (R0 path) if workspace too small ----
__global__ void build_hist_dev(const int* __restrict__ coords, const float* __restrict__ vals,
                               float* __restrict__ hist, int n) {
    int i = blockIdx.x * blockDim.x + threadIdx.x;
    if (i >= n) return;
    atomicAdd(&hist[pattern_of(coords + (size_t)i * REL_W)], vals[i]);
}
__global__ void gather_coord(const int* __restrict__ queries, const float* __restrict__ hist,
                             float* __restrict__ out, int n) {
    int i = blockIdx.x * blockDim.x + threadIdx.x;
    if (i >= n) return;
    out[i] = hist[pattern_of(queries + (size_t)i * REL_W)];
}

static inline size_t align_up(size_t x, size_t a) { return (x + a - 1) & ~(a - 1); }

extern "C" void kernel_launch(void* const* d_in, const int* in_sizes, int n_in,
                              void* d_out, int out_size, void* d_ws, size_t ws_size,
                              hipStream_t stream) {
    const int*   stored  = (const int*)d_in[0];   // [N_store, 16] int32
    const int*   queries = (const int*)d_in[1];   // [N_query, 16] int32
    const float* vals    = (const float*)d_in[2]; // [N_store] f32
    float*       out     = (float*)d_out;         // [N_query] f32

    int n_store = in_sizes[0] / REL_W;
    int n_query = in_sizes[1] / REL_W;

    // workspace layout
    size_t off_pat_s = 0;
    size_t off_hists = align_up(off_pat_s + (size_t)n_store * 2, 256);
    size_t off_final = off_hists + (size_t)NPART * NSLICES * BPP * sizeof(float);
    size_t need      = off_final + (size_t)NBINS * sizeof(float);

    if (ws_size >= need) {
        unsigned short* pat_s = (unsigned short*)((char*)d_ws + off_pat_s);
        float* part_hists     = (float*)((char*)d_ws + off_hists);
        float* final_h        = (float*)((char*)d_ws + off_final);

        int eblocks = (n_store + BLK * 4 - 1) / (BLK * 4);
        int gblocks = (n_query + BLK * 4 - 1) / (BLK * 4);
        extract_stored<<<eblocks, BLK, 0, stream>>>(stored, pat_s, n_store);
        build_parts<<<NPART * NSLICES, BUILD_BLK, 0, stream>>>(pat_s, vals, part_hists, n_store);
        reduce_parts<<<NBINS / BLK, BLK, 0, stream>>>(part_hists, final_h);
        gather_fused<<<gblocks, BLK, 0, stream>>>(queries, final_h, out, n_query);
    } else {
        float* hist = (float*)d_ws;
        hipMemsetAsync(d_ws, 0, NBINS * sizeof(float), stream);
        build_hist_dev<<<(n_store + BLK - 1) / BLK, BLK, 0, stream>>>(stored, vals, hist, n_store);
        gather_coord<<<(n_query + BLK - 1) / BLK, BLK, 0, stream>>>(queries, hist, out, n_query);
    }
}

// Round 7
// 81.243 us; speedup vs baseline: 1.2257x; 1.2257x over previous
//
#include <hip/hip_runtime.h>

// Coords are all {0,1}; STRIDES is a mixed-radix positional encoding, so each
// row maps bijectively to a 16-bit pattern. Whole op = 65536-bin float
// histogram + gather.
//
// R0-R2: global fp32 atomicAdd executes at the memory-side coherence point
// regardless of scope (~19G ops/s cap) -> no global atomics anywhere.
// R4: LDS-partitioned build (8 parts x 8192 bins, 1024-thr blocks) works.
// R4/R5 lesson: row-per-thread loads put lanes 64-256B apart -> 64 cacheline
// requests per wave instruction -> ~2.7 TB/s cap. R6: one thread per int4
// (lane-contiguous 16B loads, 16 lines/instr), 4-bit nibble per lane, OR-combine
// across the 4-lane group via __shfl_xor, group leader emits the pattern.

#define REL_W 16
#define NBINS 65536
#define NPART 8
#define BPP 8192        // bins per partition (32 KB as floats)
#define NSLICES 64
#define BUILD_BLK 1024
#define BLK 256

typedef unsigned short ushort8_t __attribute__((ext_vector_type(8)));

__device__ __forceinline__ unsigned pattern_of(const int* __restrict__ row) {
    const int4* p = reinterpret_cast<const int4*>(row);
    unsigned pat = 0;
#pragma unroll
    for (int k = 0; k < 4; ++k) {
        int4 v = p[k];
        pat |= (unsigned)(v.x & 1) << (k * 4 + 0);
        pat |= (unsigned)(v.y & 1) << (k * 4 + 1);
        pat |= (unsigned)(v.z & 1) << (k * 4 + 2);
        pat |= (unsigned)(v.w & 1) << (k * 4 + 3);
    }
    return pat;
}

__device__ __forceinline__ unsigned nibble_of(int4 v) {
    return (unsigned)(v.x & 1) | ((unsigned)(v.y & 1) << 1) |
           ((unsigned)(v.z & 1) << 2) | ((unsigned)(v.w & 1) << 3);
}

// one thread per int4 (quarter-row); 4-lane group -> one u16 pattern
__global__ __launch_bounds__(BLK) void extract_stored(const int* __restrict__ coords,
                                                      unsigned short* __restrict__ pats, int n) {
    int g = blockIdx.x * blockDim.x + threadIdx.x;
    int total = n * 4;                       // total int4 count (always %4 == 0)
    if (g < total) {
        int4 v = reinterpret_cast<const int4*>(coords)[g];
        unsigned k = (unsigned)g & 3;        // quarter index == lane&3 (4-aligned groups)
        unsigned val = nibble_of(v) << (4 * k);
        val |= __shfl_xor(val, 1);
        val |= __shfl_xor(val, 2);
        if (k == 0) pats[g >> 2] = (unsigned short)val;
    }
}

// gather fused with query pattern extraction (same cross-lane scheme)
__global__ __launch_bounds__(BLK) void gather_fused(const int* __restrict__ queries,
                                                    const float* __restrict__ h,
                                                    float* __restrict__ out, int n) {
    int g = blockIdx.x * blockDim.x + threadIdx.x;
    int total = n * 4;
    if (g < total) {
        int4 v = reinterpret_cast<const int4*>(queries)[g];
        unsigned k = (unsigned)g & 3;
        unsigned val = nibble_of(v) << (4 * k);
        val |= __shfl_xor(val, 1);
        val |= __shfl_xor(val, 2);
        if (k == 0) out[g >> 2] = h[val];
    }
}

__global__ __launch_bounds__(BUILD_BLK) void build_parts(const unsigned short* __restrict__ pats,
                                                         const float* __restrict__ vals,
                                                         float* __restrict__ part_hists, int n) {
    __shared__ float lh[BPP];
    unsigned part  = blockIdx.x / NSLICES;
    unsigned slice = blockIdx.x % NSLICES;
    for (int b = threadIdx.x; b < BPP; b += BUILD_BLK) lh[b] = 0.0f;
    __syncthreads();

    int per = ((n + NSLICES - 1) / NSLICES + 7) & ~7;
    int lo = (int)slice * per;
    int hi = min(n, lo + per);

    if (lo < hi) {
        int m = hi - lo;
        int nvec = m >> 3;
        const ushort8_t* pv = reinterpret_cast<const ushort8_t*>(pats + lo);
        const float4*    vv = reinterpret_cast<const float4*>(vals + lo);
        for (int v = threadIdx.x; v < nvec; v += BUILD_BLK) {
            ushort8_t p8 = pv[v];
            float4 v0 = vv[2 * v];
            float4 v1 = vv[2 * v + 1];
            float vsc[8] = {v0.x, v0.y, v0.z, v0.w, v1.x, v1.y, v1.z, v1.w};
#pragma unroll
            for (int kk = 0; kk < 8; ++kk) {
                unsigned pat = p8[kk];
                if ((pat >> 13) == part)
                    atomicAdd(&lh[pat & (BPP - 1)], vsc[kk]);   // ds_add_f32, on-CU
            }
        }
        for (int i = lo + (nvec << 3) + (int)threadIdx.x; i < hi; i += BUILD_BLK) {
            unsigned pat = pats[i];
            if ((pat >> 13) == part)
                atomicAdd(&lh[pat & (BPP - 1)], vals[i]);
        }
    }
    __syncthreads();
    float* dst = part_hists + (size_t)blockIdx.x * BPP;
    for (int b = threadIdx.x; b < BPP; b += BUILD_BLK) dst[b] = lh[b];
}

__global__ void reduce_parts(const float* __restrict__ part_hists, float* __restrict__ final_h) {
    int g = blockIdx.x * blockDim.x + threadIdx.x;   // bin 0..65535
    unsigned part = (unsigned)g >> 13;
    unsigned b = (unsigned)g & (BPP - 1);
    const float* src = part_hists + ((size_t)part * NSLICES) * BPP + b;
    float s = 0.0f;
#pragma unroll 8
    for (int sl = 0; sl < NSLICES; ++sl) s += src[(size_t)sl * BPP];
    final_h[g] = s;
}

// ---- fallback (R0 path) if workspace too small ----
__global__ void build_hist_dev(const int* __restrict__ coords, const float* __restrict__ vals,
                               float* __restrict__ hist, int n) {
    int i = blockIdx.x * blockDim.x + threadIdx.x;
    if (i >= n) return;
    atomicAdd(&hist[pattern_of(coords + (size_t)i * REL_W)], vals[i]);
}
__global__ void gather_coord(const int* __restrict__ queries, const float* __restrict__ hist,
                             float* __restrict__ out, int n) {
    int i = blockIdx.x * blockDim.x + threadIdx.x;
    if (i >= n) return;
    out[i] = hist[pattern_of(queries + (size_t)i * REL_W)];
}

static inline size_t align_up(size_t x, size_t a) { return (x + a - 1) & ~(a - 1); }

extern "C" void kernel_launch(void* const* d_in, const int* in_sizes, int n_in,
                              void* d_out, int out_size, void* d_ws, size_t ws_size,
                              hipStream_t stream) {
    const int*   stored  = (const int*)d_in[0];   // [N_store, 16] int32
    const int*   queries = (const int*)d_in[1];   // [N_query, 16] int32
    const float* vals    = (const float*)d_in[2]; // [N_store] f32
    float*       out     = (float*)d_out;         // [N_query] f32

    int n_store = in_sizes[0] / REL_W;
    int n_query = in_sizes[1] / REL_W;

    // workspace layout
    size_t off_pat_s = 0;
    size_t off_hists = align_up(off_pat_s + (size_t)n_store * 2, 256);
    size_t off_final = off_hists + (size_t)NPART * NSLICES * BPP * sizeof(float);
    size_t need      = off_final + (size_t)NBINS * sizeof(float);

    if (ws_size >= need) {
        unsigned short* pat_s = (unsigned short*)((char*)d_ws + off_pat_s);
        float* part_hists     = (float*)((char*)d_ws + off_hists);
        float* final_h        = (float*)((char*)d_ws + off_final);

        int eblocks = (n_store * 4 + BLK - 1) / BLK;
        int gblocks = (n_query * 4 + BLK - 1) / BLK;
        extract_stored<<<eblocks, BLK, 0, stream>>>(stored, pat_s, n_store);
        build_parts<<<NPART * NSLICES, BUILD_BLK, 0, stream>>>(pat_s, vals, part_hists, n_store);
        reduce_parts<<<NBINS / BLK, BLK, 0, stream>>>(part_hists, final_h);
        gather_fused<<<gblocks, BLK, 0, stream>>>(queries, final_h, out, n_query);
    } else {
        float* hist = (float*)d_ws;
        hipMemsetAsync(d_ws, 0, NBINS * sizeof(float), stream);
        build_hist_dev<<<(n_store + BLK - 1) / BLK, BLK, 0, stream>>>(stored, vals, hist, n_store);
        gather_coord<<<(n_query + BLK - 1) / BLK, BLK, 0, stream>>>(queries, hist, out, n_query);
    }
}